// Round 1
// 1003.405 us; speedup vs baseline: 1.0324x; 1.0324x over previous
//
#include <hip/hip_runtime.h>

#define B 8
#define L 30
#define D 512
#define NS 21
#define NI 8
#define LC 5            // L-split factor for k_u_slots
#define LPC (L / LC)    // 6 l-values per block

// ---------- Phase A: per (b,l): a_words, softmax(route logits)->wc, slots ----------
// One wave per n-subset: 64 lanes x 8 floats = 512 = D, shuffle-only reduction.
__global__ void __launch_bounds__(256) k_phase_a(
    const float* __restrict__ x,
    const float* __restrict__ w_route_ws,
    float* __restrict__ wc,
    float* __restrict__ a_words,
    float* __restrict__ slots_out) {
  __shared__ float logits[NS];
  int bl   = blockIdx.x;
  int l    = bl % L;
  int wave = threadIdx.x >> 6;
  int lane = threadIdx.x & 63;

  const float4* xp = (const float4*)(x + (size_t)bl * D) + lane * 2;
  float4 x0 = xp[0], x1 = xp[1];

  float aw = 0.f;
  if (wave == 0) {
    float s = x0.x + x0.y + x0.z + x0.w + x1.x + x1.y + x1.z + x1.w;
    #pragma unroll
    for (int o = 32; o > 0; o >>= 1) s += __shfl_xor(s, o, 64);
    aw = s / (float)D;
    if (lane == 0) a_words[bl] = aw;
  }

  for (int n = wave; n < NS; n += 4) {
    const float4* wp = (const float4*)(w_route_ws + (size_t)(l * NS + n) * D) + lane * 2;
    float4 w0 = wp[0], w1 = wp[1];
    float q = w0.x * x0.x + w0.y * x0.y + w0.z * x0.z + w0.w * x0.w
            + w1.x * x1.x + w1.y * x1.y + w1.z * x1.z + w1.w * x1.w;
    #pragma unroll
    for (int o = 32; o > 0; o >>= 1) q += __shfl_xor(q, o, 64);
    if (lane == 0) logits[n] = q;
  }
  __syncthreads();

  if (threadIdx.x == 0) {
    float m = logits[0]; int am = 0;
    #pragma unroll
    for (int n = 1; n < NS; n++) if (logits[n] > m) { m = logits[n]; am = n; }
    float e[NS]; float se = 0.f;
    #pragma unroll
    for (int n = 0; n < NS; n++) { e[n] = __expf(logits[n] - m); se += e[n]; }
    float sc = aw / se;  // wc = softmax * a_words
    #pragma unroll
    for (int n = 0; n < NS; n++) wc[(size_t)bl * NS + n] = e[n] * sc;
    slots_out[bl] = (float)am;  // argmax(c_ws) == argmax(logits)
  }
}

// ---------- Stats 1: weighted_c[b,n], a_slots[b,n] ----------
__global__ void k_stats1(const float* __restrict__ wc,
                         const float* __restrict__ a_words,
                         float* __restrict__ weighted_c,
                         float* __restrict__ a_slots) {
  __shared__ float aw_sum[B];
  int t = threadIdx.x;
  if (t < B) {
    float s = 0.f;
    for (int l = 0; l < L; l++) s += a_words[t * L + l];
    aw_sum[t] = s;
  }
  __syncthreads();
  if (t < B * NS) {
    int b = t / NS, n = t % NS;
    float s = 0.f;
    for (int l = 0; l < L; l++) s += wc[(size_t)(b * L + l) * NS + n];
    weighted_c[t] = s;
    a_slots[t] = s / aw_sum[b];
  }
}

// ---------- Phase B (heavy): partial u_slots over an L-chunk.
// grid = NS * 32 * LC (3360 blocks, ~13/CU); block = 256 thr (4 waves);
// wave handles 4 consecutive i-rows for ALL 8 batches; each W element read once.
__global__ void __launch_bounds__(256) k_u_slots(
    const float* __restrict__ x,
    const float* __restrict__ w_pose_ws,
    const float* __restrict__ wc,
    float* __restrict__ u_part) {
  __shared__ float lwc[B * L];  // wc[b,l,n] for this block's n
  int bid   = blockIdx.x;
  int n     = bid / (32 * LC);
  int rem   = bid % (32 * LC);
  int itile = rem / LC;
  int lc    = rem % LC;
  int wave  = threadIdx.x >> 6;
  int lane  = threadIdx.x & 63;
  int i0    = itile * 16 + wave * 4;

  if (threadIdx.x < B * L) lwc[threadIdx.x] = wc[(size_t)threadIdx.x * NS + n];
  __syncthreads();

  float acc[4][B];
  #pragma unroll
  for (int r = 0; r < 4; r++)
    #pragma unroll
    for (int b = 0; b < B; b++) acc[r][b] = 0.f;

  int l0 = lc * LPC;
  for (int l = l0; l < l0 + LPC; l++) {
    const float* wrow = w_pose_ws + ((size_t)(l * NS + n) * D + i0) * D;
    float4 w0[4], w1[4];
    #pragma unroll
    for (int r = 0; r < 4; r++) {
      const float4* wp = (const float4*)(wrow + (size_t)r * D) + lane * 2;
      w0[r] = wp[0]; w1[r] = wp[1];
    }
    #pragma unroll
    for (int b = 0; b < B; b++) {
      const float4* xp = (const float4*)(x + (size_t)(b * L + l) * D) + lane * 2;
      float4 x0 = xp[0], x1 = xp[1];
      float wcl = lwc[b * L + l];
      #pragma unroll
      for (int r = 0; r < 4; r++) {
        float t = w0[r].x * x0.x + w0[r].y * x0.y + w0[r].z * x0.z + w0[r].w * x0.w
                + w1[r].x * x1.x + w1[r].y * x1.y + w1[r].z * x1.z + w1[r].w * x1.w;
        acc[r][b] += wcl * t;
      }
    }
  }
  #pragma unroll
  for (int r = 0; r < 4; r++)
    #pragma unroll
    for (int b = 0; b < B; b++)
      #pragma unroll
      for (int o = 32; o > 0; o >>= 1) acc[r][b] += __shfl_xor(acc[r][b], o, 64);
  if (lane == 0) {
    #pragma unroll
    for (int r = 0; r < 4; r++)
      #pragma unroll
      for (int b = 0; b < B; b++)
        u_part[(((size_t)lc * B + b) * NS + n) * D + (i0 + r)] = acc[r][b];
  }
}

// ---------- Combine L-chunk partials and divide by weighted_c ----------
__global__ void k_div_u(const float* __restrict__ u_part,
                        const float* __restrict__ weighted_c,
                        float* __restrict__ u_slots) {
  int bn = blockIdx.x;  // b*NS + n
  int b  = bn / NS, n = bn % NS;
  float wcn = weighted_c[bn];
  for (int k = threadIdx.x; k < D; k += 256) {
    float s = 0.f;
    #pragma unroll
    for (int lc = 0; lc < LC; lc++)
      s += u_part[(((size_t)lc * B + b) * NS + n) * D + k];
    u_slots[(size_t)bn * D + k] = s / wcn;
  }
}

// ---------- Phase C: per (b,s): softmax over NI of route_si logits -> wc2 ----------
__global__ void __launch_bounds__(256) k_route_si(
    const float* __restrict__ u_slots,
    const float* __restrict__ w_route_si,
    const float* __restrict__ a_slots,
    float* __restrict__ wc2) {
  __shared__ float logits[NI];
  int bs   = blockIdx.x;  // = b*NS + s
  int s    = bs % NS;
  int wave = threadIdx.x >> 6;
  int lane = threadIdx.x & 63;

  const float4* up = (const float4*)(u_slots + (size_t)bs * D) + lane * 2;
  float4 u0 = up[0], u1 = up[1];

  for (int i = wave; i < NI; i += 4) {
    const float4* wp = (const float4*)(w_route_si + (size_t)(s * NI + i) * D) + lane * 2;
    float4 w0 = wp[0], w1 = wp[1];
    float q = w0.x * u0.x + w0.y * u0.y + w0.z * u0.z + w0.w * u0.w
            + w1.x * u1.x + w1.y * u1.y + w1.z * u1.z + w1.w * u1.w;
    #pragma unroll
    for (int o = 32; o > 0; o >>= 1) q += __shfl_xor(q, o, 64);
    if (lane == 0) logits[i] = q;
  }
  __syncthreads();
  if (threadIdx.x == 0) {
    float m = logits[0];
    #pragma unroll
    for (int i = 1; i < NI; i++) m = fmaxf(m, logits[i]);
    float e[NI]; float se = 0.f;
    #pragma unroll
    for (int i = 0; i < NI; i++) { e[i] = __expf(logits[i] - m); se += e[i]; }
    float sc = a_slots[bs] / se;
    #pragma unroll
    for (int i = 0; i < NI; i++) wc2[(size_t)bs * NI + i] = e[i] * sc;
  }
}

// ---------- Stats 2: weighted_c2[b,i], max_idx[b] ----------
__global__ void k_stats2(const float* __restrict__ wc2,
                         const float* __restrict__ a_slots,
                         float* __restrict__ weighted_c2,
                         int* __restrict__ max_idx) {
  __shared__ float asum[B];
  __shared__ float ai[B * NI];
  int t = threadIdx.x;
  if (t < B) {
    float s = 0.f;
    for (int n = 0; n < NS; n++) s += a_slots[t * NS + n];
    asum[t] = s;
  }
  float w = 0.f;
  if (t < B * NI) {
    int b = t / NI, i = t % NI;
    for (int ss = 0; ss < NS; ss++) w += wc2[(size_t)(b * NS + ss) * NI + i];
    weighted_c2[t] = w;
  }
  __syncthreads();
  if (t < B * NI) ai[t] = w / asum[t / NI];
  __syncthreads();
  if (t < B) {
    float m = ai[t * NI]; int am = 0;
    #pragma unroll
    for (int i = 1; i < NI; i++) { float v = ai[t * NI + i]; if (v > m) { m = v; am = i; } }
    max_idx[t] = am;
  }
}

// ---------- Column sums of w_pose_si for selected intents only.
// colsum[s,i,k] = sum_j W_si[s,i,j,k] is batch-independent; compute once per
// selected (s,i) with float4 loads; early-exit unselected i (never read later).
// grid = NS*NI*4 (j split 4-way); block = 256 (128 k-float4 x 2 j-groups).
__global__ void __launch_bounds__(256) k_colsum(
    const float* __restrict__ w_pose_si,
    const int* __restrict__ max_idx,
    float* __restrict__ colsum_part) {
  int blk = blockIdx.x;
  int si  = blk >> 2;        // s*NI + i
  int i   = si & (NI - 1);
  int jc  = blk & 3;
  bool sel = false;
  #pragma unroll
  for (int b = 0; b < B; b++) sel |= (max_idx[b] == i);
  if (!sel) return;

  int t  = threadIdx.x;
  int k4 = t & 127;          // float4 index over k (512/4)
  int jg = t >> 7;           // 0/1: two j-groups of 64
  const float4* wb = (const float4*)(w_pose_si + (size_t)si * D * D) + k4;
  int j0 = jc * 128 + jg * 64;
  float4 s = {0.f, 0.f, 0.f, 0.f};
  #pragma unroll 4
  for (int j = j0; j < j0 + 64; j++) {
    float4 v = wb[(size_t)j * (D / 4)];
    s.x += v.x; s.y += v.y; s.z += v.z; s.w += v.w;
  }
  __shared__ float4 part[128];
  if (jg == 0) part[k4] = s;
  __syncthreads();
  if (jg == 1) {
    float4 p = part[k4];
    p.x += s.x; p.y += s.y; p.z += s.z; p.w += s.w;
    ((float4*)colsum_part)[(size_t)(jc * NS * NI + si) * (D / 4) + k4] = p;
  }
}

// ---------- Final: poses + cls residual, no atomics ----------
__global__ void k_final2(const float* __restrict__ cls,
                         const float* __restrict__ u_slots,
                         const float* __restrict__ wc2,
                         const float* __restrict__ weighted_c2,
                         const int* __restrict__ max_idx,
                         const float* __restrict__ colsum_part,
                         float* __restrict__ out_intents) {
  int b = blockIdx.x, k = threadIdx.x;  // 512 threads
  int i = max_idx[b];
  float acc = 0.f;
  for (int s = 0; s < NS; s++) {
    float cs = 0.f;
    #pragma unroll
    for (int jc = 0; jc < 4; jc++)
      cs += colsum_part[(size_t)(jc * NS * NI + s * NI + i) * D + k];
    acc += wc2[(size_t)(b * NS + s) * NI + i] *
           u_slots[(size_t)(b * NS + s) * D + k] * cs;
  }
  out_intents[b * D + k] = cls[b * D + k] + acc / weighted_c2[b * NI + i];
}

extern "C" void kernel_launch(void* const* d_in, const int* in_sizes, int n_in,
                              void* d_out, int out_size, void* d_ws, size_t ws_size,
                              hipStream_t stream) {
  const float* x    = (const float*)d_in[0];  // (B,L,D)
  const float* cls  = (const float*)d_in[1];  // (B,D)
  const float* wrws = (const float*)d_in[2];  // (L,NS,D)
  const float* wpws = (const float*)d_in[3];  // (L,NS,D,D)
  const float* wrsi = (const float*)d_in[4];  // (NS,NI,D)
  const float* wpsi = (const float*)d_in[5];  // (NS,NI,D,D)

  float* out         = (float*)d_out;
  float* slots_out   = out;           // B*L = 240 (ints as float)
  float* intents_out = out + B * L;   // B*D = 4096

  float* wsf         = (float*)d_ws;
  float* wc          = wsf;                     // B*L*NS        = 5040
  float* a_words     = wc + B * L * NS;         // B*L           = 240
  float* weighted_c  = a_words + B * L;         // B*NS          = 168
  float* a_slots     = weighted_c + B * NS;     // B*NS          = 168
  float* u_slots     = a_slots + B * NS;        // B*NS*D        = 86016
  float* u_part      = u_slots + B * NS * D;    // LC*B*NS*D     = 430080
  float* wc2         = u_part + LC * B * NS * D;// B*NS*NI       = 1344
  float* weighted_c2 = wc2 + B * NS * NI;       // B*NI          = 64
  int*   max_idx     = (int*)(weighted_c2 + B * NI);             // 8
  float* colsum_part = (float*)(max_idx + 8);   // 4*NS*NI*D     = 344064

  k_phase_a<<<B * L, 256, 0, stream>>>(x, wrws, wc, a_words, slots_out);
  k_stats1<<<1, 256, 0, stream>>>(wc, a_words, weighted_c, a_slots);
  k_u_slots<<<NS * 32 * LC, 256, 0, stream>>>(x, wpws, wc, u_part);
  k_div_u<<<B * NS, 256, 0, stream>>>(u_part, weighted_c, u_slots);
  k_route_si<<<B * NS, 256, 0, stream>>>(u_slots, wrsi, a_slots, wc2);
  k_stats2<<<1, 256, 0, stream>>>(wc2, a_slots, weighted_c2, max_idx);
  k_colsum<<<NS * NI * 4, 256, 0, stream>>>(wpsi, max_idx, colsum_part);
  k_final2<<<B, 512, 0, stream>>>(cls, u_slots, wc2, weighted_c2, max_idx,
                                  colsum_part, intents_out);
}

// Round 2
// 953.711 us; speedup vs baseline: 1.0862x; 1.0521x over previous
//
#include <hip/hip_runtime.h>

#define B 8
#define L 30
#define D 512
#define NS 21
#define NI 8
#define LC 6            // L-split factor for k_u_slots
#define LPC (L / LC)    // 5 l-values per block

// ---------- Phase A: per (b,l): a_words, softmax(route logits)->wc, slots ----------
// One wave per n-subset; contiguous [lane]/[lane+64] float4 split (dense 1KB/inst).
__global__ void __launch_bounds__(256) k_phase_a(
    const float* __restrict__ x,
    const float* __restrict__ w_route_ws,
    float* __restrict__ wc,
    float* __restrict__ a_words,
    float* __restrict__ slots_out) {
  __shared__ float logits[NS];
  int bl   = blockIdx.x;
  int l    = bl % L;
  int wave = threadIdx.x >> 6;
  int lane = threadIdx.x & 63;

  const float4* xp = (const float4*)(x + (size_t)bl * D);
  float4 x0 = xp[lane], x1 = xp[lane + 64];

  float aw = 0.f;
  if (wave == 0) {
    float s = x0.x + x0.y + x0.z + x0.w + x1.x + x1.y + x1.z + x1.w;
    #pragma unroll
    for (int o = 32; o > 0; o >>= 1) s += __shfl_xor(s, o, 64);
    aw = s / (float)D;
    if (lane == 0) a_words[bl] = aw;
  }

  for (int n = wave; n < NS; n += 4) {
    const float4* wp = (const float4*)(w_route_ws + (size_t)(l * NS + n) * D);
    float4 w0 = wp[lane], w1 = wp[lane + 64];
    float q = w0.x * x0.x + w0.y * x0.y + w0.z * x0.z + w0.w * x0.w
            + w1.x * x1.x + w1.y * x1.y + w1.z * x1.z + w1.w * x1.w;
    #pragma unroll
    for (int o = 32; o > 0; o >>= 1) q += __shfl_xor(q, o, 64);
    if (lane == 0) logits[n] = q;
  }
  __syncthreads();

  if (threadIdx.x == 0) {
    float m = logits[0]; int am = 0;
    #pragma unroll
    for (int n = 1; n < NS; n++) if (logits[n] > m) { m = logits[n]; am = n; }
    float e[NS]; float se = 0.f;
    #pragma unroll
    for (int n = 0; n < NS; n++) { e[n] = __expf(logits[n] - m); se += e[n]; }
    float sc = aw / se;  // wc = softmax * a_words
    #pragma unroll
    for (int n = 0; n < NS; n++) wc[(size_t)bl * NS + n] = e[n] * sc;
    slots_out[bl] = (float)am;  // argmax(c_ws) == argmax(logits)
  }
}

// ---------- Phase B (heavy): partial u_slots over an L-chunk.
// grid = NS * 32 * LC (4032 blocks, ~15.7/CU); block = 256 thr (4 waves);
// wave handles 4 consecutive i-rows for ALL 8 batches; each W element read once.
// Loads use dense [lane]/[lane+64] split: every float4 inst = contiguous 1KB.
__global__ void __launch_bounds__(256) k_u_slots(
    const float* __restrict__ x,
    const float* __restrict__ w_pose_ws,
    const float* __restrict__ wc,
    float* __restrict__ u_part) {
  __shared__ float lwc[B * L];  // wc[b,l,n] for this block's n
  int bid   = blockIdx.x;
  int n     = bid / (32 * LC);
  int rem   = bid % (32 * LC);
  int itile = rem / LC;
  int lc    = rem % LC;
  int wave  = threadIdx.x >> 6;
  int lane  = threadIdx.x & 63;
  int i0    = itile * 16 + wave * 4;

  if (threadIdx.x < B * L) lwc[threadIdx.x] = wc[(size_t)threadIdx.x * NS + n];
  __syncthreads();

  float acc[4][B];
  #pragma unroll
  for (int r = 0; r < 4; r++)
    #pragma unroll
    for (int b = 0; b < B; b++) acc[r][b] = 0.f;

  int l0 = lc * LPC;
  for (int l = l0; l < l0 + LPC; l++) {
    const float* wrow = w_pose_ws + ((size_t)(l * NS + n) * D + i0) * D;
    float4 w0[4], w1[4];
    #pragma unroll
    for (int r = 0; r < 4; r++) {
      const float4* wp = (const float4*)(wrow + (size_t)r * D);
      w0[r] = wp[lane]; w1[r] = wp[lane + 64];
    }
    #pragma unroll
    for (int b = 0; b < B; b++) {
      const float4* xp = (const float4*)(x + (size_t)(b * L + l) * D);
      float4 x0 = xp[lane], x1 = xp[lane + 64];
      float wcl = lwc[b * L + l];
      #pragma unroll
      for (int r = 0; r < 4; r++) {
        float t = w0[r].x * x0.x + w0[r].y * x0.y + w0[r].z * x0.z + w0[r].w * x0.w
                + w1[r].x * x1.x + w1[r].y * x1.y + w1[r].z * x1.z + w1[r].w * x1.w;
        acc[r][b] += wcl * t;
      }
    }
  }
  #pragma unroll
  for (int r = 0; r < 4; r++)
    #pragma unroll
    for (int b = 0; b < B; b++)
      #pragma unroll
      for (int o = 32; o > 0; o >>= 1) acc[r][b] += __shfl_xor(acc[r][b], o, 64);
  if (lane == 0) {
    #pragma unroll
    for (int r = 0; r < 4; r++)
      #pragma unroll
      for (int b = 0; b < B; b++)
        u_part[(((size_t)lc * B + b) * NS + n) * D + (i0 + r)] = acc[r][b];
  }
}

// ---------- Combine L-chunk partials, compute weighted_c/a_slots inline, divide ----------
// (folds old k_stats1: weighted_c[bn] = sum_l wc[b,l,n]; a_slots = / sum_l a_words[b,l])
__global__ void __launch_bounds__(256) k_div_u(
    const float* __restrict__ u_part,
    const float* __restrict__ wc,
    const float* __restrict__ a_words,
    float* __restrict__ a_slots,
    float* __restrict__ u_slots) {
  __shared__ float s_wcn;
  int bn = blockIdx.x;  // b*NS + n
  int b  = bn / NS, n = bn % NS;
  int t  = threadIdx.x;
  if (t < 64) {
    float sw = 0.f, sa = 0.f;
    if (t < L) {
      sw = wc[(size_t)(b * L + t) * NS + n];
      sa = a_words[b * L + t];
    }
    #pragma unroll
    for (int o = 32; o > 0; o >>= 1) {
      sw += __shfl_xor(sw, o, 64);
      sa += __shfl_xor(sa, o, 64);
    }
    if (t == 0) { s_wcn = sw; a_slots[bn] = sw / sa; }
  }
  __syncthreads();
  float inv = 1.f / s_wcn;
  for (int k = t; k < D; k += 256) {
    float s = 0.f;
    #pragma unroll
    for (int lc = 0; lc < LC; lc++)
      s += u_part[(((size_t)lc * B + b) * NS + n) * D + k];
    u_slots[(size_t)bn * D + k] = s * inv;
  }
}

// ---------- Phase C: per (b,s): softmax over NI of route_si logits -> wc2 ----------
__global__ void __launch_bounds__(256) k_route_si(
    const float* __restrict__ u_slots,
    const float* __restrict__ w_route_si,
    const float* __restrict__ a_slots,
    float* __restrict__ wc2) {
  __shared__ float logits[NI];
  int bs   = blockIdx.x;  // = b*NS + s
  int s    = bs % NS;
  int wave = threadIdx.x >> 6;
  int lane = threadIdx.x & 63;

  const float4* up = (const float4*)(u_slots + (size_t)bs * D);
  float4 u0 = up[lane], u1 = up[lane + 64];

  for (int i = wave; i < NI; i += 4) {
    const float4* wp = (const float4*)(w_route_si + (size_t)(s * NI + i) * D);
    float4 w0 = wp[lane], w1 = wp[lane + 64];
    float q = w0.x * u0.x + w0.y * u0.y + w0.z * u0.z + w0.w * u0.w
            + w1.x * u1.x + w1.y * u1.y + w1.z * u1.z + w1.w * u1.w;
    #pragma unroll
    for (int o = 32; o > 0; o >>= 1) q += __shfl_xor(q, o, 64);
    if (lane == 0) logits[i] = q;
  }
  __syncthreads();
  if (threadIdx.x == 0) {
    float m = logits[0];
    #pragma unroll
    for (int i = 1; i < NI; i++) m = fmaxf(m, logits[i]);
    float e[NI]; float se = 0.f;
    #pragma unroll
    for (int i = 0; i < NI; i++) { e[i] = __expf(logits[i] - m); se += e[i]; }
    float sc = a_slots[bs] / se;
    #pragma unroll
    for (int i = 0; i < NI; i++) wc2[(size_t)bs * NI + i] = e[i] * sc;
  }
}

// ---------- Stats 2: weighted_c2[b,i], max_idx[b] ----------
__global__ void k_stats2(const float* __restrict__ wc2,
                         const float* __restrict__ a_slots,
                         float* __restrict__ weighted_c2,
                         int* __restrict__ max_idx) {
  __shared__ float asum[B];
  __shared__ float ai[B * NI];
  int t = threadIdx.x;
  if (t < B) {
    float s = 0.f;
    for (int n = 0; n < NS; n++) s += a_slots[t * NS + n];
    asum[t] = s;
  }
  float w = 0.f;
  if (t < B * NI) {
    int b = t / NI, i = t % NI;
    for (int ss = 0; ss < NS; ss++) w += wc2[(size_t)(b * NS + ss) * NI + i];
    weighted_c2[t] = w;
  }
  __syncthreads();
  if (t < B * NI) ai[t] = w / asum[t / NI];
  __syncthreads();
  if (t < B) {
    float m = ai[t * NI]; int am = 0;
    #pragma unroll
    for (int i = 1; i < NI; i++) { float v = ai[t * NI + i]; if (v > m) { m = v; am = i; } }
    max_idx[t] = am;
  }
}

// ---------- Column sums of w_pose_si for selected intents only. ----------
// colsum[s,i,k] = sum_j W_si[s,i,j,k]; batch-independent; early-exit unselected i.
// grid = NS*NI*4 (j split 4-way); block = 256 (128 k-float4 x 2 j-groups).
__global__ void __launch_bounds__(256) k_colsum(
    const float* __restrict__ w_pose_si,
    const int* __restrict__ max_idx,
    float* __restrict__ colsum_part) {
  int blk = blockIdx.x;
  int si  = blk >> 2;        // s*NI + i
  int i   = si & (NI - 1);
  int jc  = blk & 3;
  bool sel = false;
  #pragma unroll
  for (int b = 0; b < B; b++) sel |= (max_idx[b] == i);
  if (!sel) return;

  int t  = threadIdx.x;
  int k4 = t & 127;          // float4 index over k (512/4)
  int jg = t >> 7;           // 0/1: two j-groups of 64
  const float4* wb = (const float4*)(w_pose_si + (size_t)si * D * D) + k4;
  int j0 = jc * 128 + jg * 64;
  float4 s = {0.f, 0.f, 0.f, 0.f};
  #pragma unroll 4
  for (int j = j0; j < j0 + 64; j++) {
    float4 v = wb[(size_t)j * (D / 4)];
    s.x += v.x; s.y += v.y; s.z += v.z; s.w += v.w;
  }
  __shared__ float4 part[128];
  if (jg == 0) part[k4] = s;
  __syncthreads();
  if (jg == 1) {
    float4 p = part[k4];
    p.x += s.x; p.y += s.y; p.z += s.z; p.w += s.w;
    ((float4*)colsum_part)[(size_t)(jc * NS * NI + si) * (D / 4) + k4] = p;
  }
}

// ---------- Final: poses + cls residual, no atomics ----------
__global__ void k_final2(const float* __restrict__ cls,
                         const float* __restrict__ u_slots,
                         const float* __restrict__ wc2,
                         const float* __restrict__ weighted_c2,
                         const int* __restrict__ max_idx,
                         const float* __restrict__ colsum_part,
                         float* __restrict__ out_intents) {
  int b = blockIdx.x, k = threadIdx.x;  // 512 threads
  int i = max_idx[b];
  float acc = 0.f;
  for (int s = 0; s < NS; s++) {
    float cs = 0.f;
    #pragma unroll
    for (int jc = 0; jc < 4; jc++)
      cs += colsum_part[(size_t)(jc * NS * NI + s * NI + i) * D + k];
    acc += wc2[(size_t)(b * NS + s) * NI + i] *
           u_slots[(size_t)(b * NS + s) * D + k] * cs;
  }
  out_intents[b * D + k] = cls[b * D + k] + acc / weighted_c2[b * NI + i];
}

extern "C" void kernel_launch(void* const* d_in, const int* in_sizes, int n_in,
                              void* d_out, int out_size, void* d_ws, size_t ws_size,
                              hipStream_t stream) {
  const float* x    = (const float*)d_in[0];  // (B,L,D)
  const float* cls  = (const float*)d_in[1];  // (B,D)
  const float* wrws = (const float*)d_in[2];  // (L,NS,D)
  const float* wpws = (const float*)d_in[3];  // (L,NS,D,D)
  const float* wrsi = (const float*)d_in[4];  // (NS,NI,D)
  const float* wpsi = (const float*)d_in[5];  // (NS,NI,D,D)

  float* out         = (float*)d_out;
  float* slots_out   = out;           // B*L = 240 (ints as float)
  float* intents_out = out + B * L;   // B*D = 4096

  float* wsf         = (float*)d_ws;
  float* wc          = wsf;                     // B*L*NS        = 5040
  float* a_words     = wc + B * L * NS;         // B*L           = 240
  float* a_slots     = a_words + B * L;         // B*NS          = 168
  float* u_slots     = a_slots + B * NS;        // B*NS*D        = 86016
  float* u_part      = u_slots + B * NS * D;    // LC*B*NS*D     = 516096
  float* wc2         = u_part + LC * B * NS * D;// B*NS*NI       = 1344
  float* weighted_c2 = wc2 + B * NS * NI;       // B*NI          = 64
  int*   max_idx     = (int*)(weighted_c2 + B * NI);             // 8
  float* colsum_part = (float*)(max_idx + 8);   // 4*NS*NI*D     = 344064

  k_phase_a<<<B * L, 256, 0, stream>>>(x, wrws, wc, a_words, slots_out);
  k_u_slots<<<NS * 32 * LC, 256, 0, stream>>>(x, wpws, wc, u_part);
  k_div_u<<<B * NS, 256, 0, stream>>>(u_part, wc, a_words, a_slots, u_slots);
  k_route_si<<<B * NS, 256, 0, stream>>>(u_slots, wrsi, a_slots, wc2);
  k_stats2<<<1, 256, 0, stream>>>(wc2, a_slots, weighted_c2, max_idx);
  k_colsum<<<NS * NI * 4, 256, 0, stream>>>(wpsi, max_idx, colsum_part);
  k_final2<<<B, 512, 0, stream>>>(cls, u_slots, wc2, weighted_c2, max_idx,
                                  colsum_part, intents_out);
}